// Round 7
// baseline (926.676 us; speedup 1.0000x reference)
//
#include <hip/hip_runtime.h>

// NeuralBPDecoder: sparse BP over a 0.1%-dense parity matrix.
// Round 13: SCAN MLP fix. r10-r12 post-mortem: time pinned at ~375us while
// P2 went IF->L2-local, barriers halved, FETCH swung 274-467MB -> the
// constant ~330us is the P1a scan, which is MLP-LATENCY-bound, not BW-bound:
// ~4x16B loads in flight/wave = 4096 waves x 64B / ~600cy = ~1.0-1.6 TB/s
// -> 512MB in ~320-490us. Fix: stage H through LDS via global_load_lds
// (1KB per instruction per wave) in a per-wave 2-slot ring with counted
// s_waitcnt vmcnt(1): next chunk's DMA is always in flight while the
// current chunk is ballot-processed from LDS. Effective in-flight ~2KB/wave
// -> MLP ceiling ~30TB/s; scan becomes HBM/L3-bound (~80-100us). The loop
// has NO other vmem ops (edge compaction is LDS-only) and a vmcnt(0) drain
// precedes it, so the counted waits are exact. Staging = 32KB extra LDS
// (total ~116KB, still 1 block/CU -> XCD pinning preserved). P2 (XCD-local
// sc0 gathers), CSR build, barriers identical to round 12.

#define C_NUM 8192
#define V_NUM 16384
#define B_NUM 32
#define RW 64   // storage slots per check row (mean nnz 16.4)
#define CW 32   // storage slots per var col  (mean nnz  8.2)

#define RQ 12   // u64 idx batches per row in LDS: 48 idx (max row nnz ~33)
#define CQ 8    // u64 idx batches per col in LDS: 32 idx (max col nnz ~20)
#define RQ_S 13 // LDS row stride (u64) - breaks bank alignment
#define CQ_S 9  // LDS col stride (u64)

#define NBLK 256
#define NTHR 1024
#define NTH (NBLK * NTHR)   // 262144 threads, 16 waves/CU
#define NWAVE (NTH / 64)    // 4096 waves

#define WCAP 256            // LDS edge slots per wave (mean 32.8, >30 sigma safe)
#define SCAN_ITERS 128      // 1KB chunks per wave: 512MB / (4096 waves * 1KB)

#define BEL_SL (16400 * 4)  // floats per bel slice (dummy vi=16384 pad inside)
#define CMS_SL (8200 * 4)   // floats per cms slice (dummy ci=8192 pad inside)

typedef unsigned short u16;
typedef unsigned int u32;
typedef unsigned long long u64;

#define ZERO_WORDS ((C_NUM + V_NUM))        // row_cnt+col_cnt ints only
#define NBAR 32
#define BAR_STRIDE 64              // u32s between counters (256 B)

__device__ __forceinline__ float agent_ldf(const float* p) {
    return __hip_atomic_load(p, __ATOMIC_RELAXED, __HIP_MEMORY_SCOPE_AGENT);
}
__device__ __forceinline__ void agent_stf(float* p, float v) {
    __hip_atomic_store(p, v, __ATOMIC_RELAXED, __HIP_MEMORY_SCOPE_AGENT);
}
__device__ __forceinline__ u64 agent_ld64(const u64* p) {
    return __hip_atomic_load(p, __ATOMIC_RELAXED, __HIP_MEMORY_SCOPE_AGENT);
}
__device__ __forceinline__ int agent_ldi(const int* p) {
    return __hip_atomic_load(p, __ATOMIC_RELAXED, __HIP_MEMORY_SCOPE_AGENT);
}
__device__ __forceinline__ void agent_st32(u32* p, u32 v) {
    __hip_atomic_store(p, v, __ATOMIC_RELAXED, __HIP_MEMORY_SCOPE_AGENT);
}
__device__ __forceinline__ void agent_st16(u16* p, u16 v) {
    __hip_atomic_store(p, v, __ATOMIC_RELAXED, __HIP_MEMORY_SCOPE_AGENT);
}

// Relaxed-only grid barrier. Sound because: __syncthreads drains vmcnt in
// every thread (stores committed to their coherence point) before thread 0
// signals; cross-XCD data uses sc1 (IF); intra-XCD data only needs L2.
__device__ __forceinline__ void grid_barrier(u32* bars, int id) {
    __syncthreads();
    if (threadIdx.x == 0) {
        u32* base = bars + id * 8 * BAR_STRIDE;
        asm volatile("s_waitcnt vmcnt(0) lgkmcnt(0)" ::: "memory");
        __hip_atomic_fetch_add(base + (blockIdx.x & 7) * BAR_STRIDE, 1u,
                               __ATOMIC_RELAXED, __HIP_MEMORY_SCOPE_AGENT);
        u32 sum;
        do {
            sum = 0;
#pragma unroll
            for (int g = 0; g < 8; ++g)
                sum += __hip_atomic_load(base + g * BAR_STRIDE,
                                         __ATOMIC_RELAXED, __HIP_MEMORY_SCOPE_AGENT);
            if (sum < (u32)NBLK) __builtin_amdgcn_s_sleep(4);
        } while (sum < (u32)NBLK);
        asm volatile("" ::: "memory");
    }
    __syncthreads();
}

__device__ __forceinline__ float fast_tanh_half(float x) {
    float ax = fabsf(x);
    float e = __expf(-ax);
    return copysignf((1.0f - e) / (1.0f + e), x);
}

// 4-wide gather. LOCAL: sc0 = SE scope (bypass CU L1, served by XCD L2).
// FALLBACK: agent (sc1 -> IF). Results flow through asm outputs, so the
// data dependence is explicit (no hoist hazard).
template<bool LOCAL>
__device__ __forceinline__ void ld4(const float* p0, const float* p1,
                                    const float* p2, const float* p3,
                                    float& r0, float& r1, float& r2, float& r3) {
    if (LOCAL) {
        asm volatile(
            "global_load_dword %0, %4, off sc0\n\t"
            "global_load_dword %1, %5, off sc0\n\t"
            "global_load_dword %2, %6, off sc0\n\t"
            "global_load_dword %3, %7, off sc0\n\t"
            "s_waitcnt vmcnt(0)"
            : "=&v"(r0), "=&v"(r1), "=&v"(r2), "=&v"(r3)
            : "v"(p0), "v"(p1), "v"(p2), "v"(p3)
            : "memory");
    } else {
        r0 = agent_ldf(p0); r1 = agent_ldf(p1);
        r2 = agent_ldf(p2); r3 = agent_ldf(p3);
    }
}

template<bool LOCAL>
__device__ __forceinline__ void decode_tail(
    int G, int R,
    const float* __restrict__ synd, const float* __restrict__ llr,
    const int* __restrict__ row_cnt, const int* __restrict__ col_cnt,
    const u16* __restrict__ row_idx, const u16* __restrict__ col_idx,
    float* __restrict__ bel_x, float* __restrict__ cms_x,
    u32* __restrict__ bars, float* __restrict__ out,
    u64* ls_row, u64* ls_col,
    float wvc, float wcv, float d)
{
    const int t = threadIdx.x;
    const int b4 = t & 3;
    const int qid = t >> 2;                  // 0..255
    float* const belS = bel_x + (size_t)G * BEL_SL;
    float* const cmsS = cms_x + (size_t)G * CMS_SL;

    // ---- copy this group's CSR indices into LDS (tails -> dummy idx) ----
    for (int e = t; e < 256 * RQ; e += NTHR) {
        int rl = e / RQ, p = e - rl * RQ;
        int c = (R << 8) + rl;
        int n = agent_ldi(&row_cnt[c]); n = n > 4 * RQ ? 4 * RQ : n;
        u64 q = agent_ld64(&((const u64*)(row_idx + (size_t)c * RW))[p]);
        int j = 4 * p;
        u64 a0 = (j + 0 < n) ? (q & 0xFFFFu) : (u64)V_NUM;
        u64 a1 = (j + 1 < n) ? ((q >> 16) & 0xFFFFu) : (u64)V_NUM;
        u64 a2 = (j + 2 < n) ? ((q >> 32) & 0xFFFFu) : (u64)V_NUM;
        u64 a3 = (j + 3 < n) ? (q >> 48) : (u64)V_NUM;
        ls_row[rl * RQ_S + p] = a0 | (a1 << 16) | (a2 << 32) | (a3 << 48);
    }
    for (int e = t; e < 512 * CQ; e += NTHR) {
        int gl = e >> 3, p = e & 7;
        int v = (gl < 256) ? ((R << 8) + gl) : (C_NUM + (R << 8) + (gl - 256));
        int n = agent_ldi(&col_cnt[v]); n = n > 4 * CQ ? 4 * CQ : n;
        u64 q = agent_ld64(&((const u64*)(col_idx + (size_t)v * CW))[p]);
        int j = 4 * p;
        u64 a0 = (j + 0 < n) ? (q & 0xFFFFu) : (u64)C_NUM;
        u64 a1 = (j + 1 < n) ? ((q >> 16) & 0xFFFFu) : (u64)C_NUM;
        u64 a2 = (j + 2 < n) ? ((q >> 32) & 0xFFFFu) : (u64)C_NUM;
        u64 a3 = (j + 3 < n) ? (q >> 48) : (u64)C_NUM;
        ls_col[gl * CQ_S + p] = a0 | (a1 << 16) | (a2 << 32) | (a3 << 48);
    }
    // ---- per-thread state ----
    const int c_my = (R << 8) + qid;
    const int v0_my = (R << 8) + qid;
    const int v1_my = C_NUM + (R << 8) + qid;
    int nrow;  { int n = agent_ldi(&row_cnt[c_my]);  nrow  = n > 4*RQ ? 4*RQ : n; }
    int ncol0; { int n = agent_ldi(&col_cnt[v0_my]); ncol0 = n > 4*CQ ? 4*CQ : n; }
    int ncol1; { int n = agent_ldi(&col_cnt[v1_my]); ncol1 = n > 4*CQ ? 4*CQ : n; }
    const int b = (G << 2) + b4;
    const float ss = 1.0f - 2.0f * synd[b * C_NUM + c_my];
    const float llr0 = llr[b * V_NUM + v0_my];
    const float llr1 = llr[b * V_NUM + v1_my];
    float bel0 = llr0, bel1 = llr1;
    if (LOCAL) {
        belS[v0_my * 4 + b4] = bel0;
        belS[v1_my * 4 + b4] = bel1;
    } else {
        agent_stf(&belS[v0_my * 4 + b4], bel0);
        agent_stf(&belS[v1_my * 4 + b4], bel1);
    }

    grid_barrier(bars, 2);   // bel init + LDS idx visible group-wide

    const u64* const rowL  = ls_row + qid * RQ_S;
    const u64* const colL0 = ls_col + qid * CQ_S;
    const u64* const colL1 = ls_col + (256 + qid) * CQ_S;
    float* const cms_own  = cmsS + c_my * 4 + b4;
    float* const bel_own0 = belS + v0_my * 4 + b4;
    float* const bel_own1 = belS + v1_my * 4 + b4;

    int barid = 3;
    for (int it = 0; it < 15; ++it) {
        // ---- v->c ----
        {
            float sum = 0.0f;
#pragma unroll
            for (int p = 0; p < RQ; ++p) {
                if (4 * p < nrow) {
                    u64 q = rowL[p];
                    const float* a0 = belS + (int)(q & 0xFFFFu) * 4 + b4;
                    const float* a1 = belS + (int)((q >> 16) & 0xFFFFu) * 4 + b4;
                    const float* a2 = belS + (int)((q >> 32) & 0xFFFFu) * 4 + b4;
                    const float* a3 = belS + (int)(q >> 48) * 4 + b4;
                    float s0, s1, s2, s3;
                    ld4<LOCAL>(a0, a1, a2, a3, s0, s1, s2, s3);
                    sum += s0; sum += s1; sum += s2; sum += s3;
                }
            }
            float m = ss * fast_tanh_half(wvc * sum);
            if (LOCAL) *cms_own = m; else agent_stf(cms_own, m);
        }
        grid_barrier(bars, barid++);

        // ---- c->v ----
        bool last = (it == 14);
        float sum0 = 0.0f, sum1 = 0.0f;
#pragma unroll
        for (int p = 0; p < CQ; ++p) {
            if (4 * p < ncol0) {
                u64 q = colL0[p];
                const float* a0 = cmsS + (int)(q & 0xFFFFu) * 4 + b4;
                const float* a1 = cmsS + (int)((q >> 16) & 0xFFFFu) * 4 + b4;
                const float* a2 = cmsS + (int)((q >> 32) & 0xFFFFu) * 4 + b4;
                const float* a3 = cmsS + (int)(q >> 48) * 4 + b4;
                float s0, s1, s2, s3;
                ld4<LOCAL>(a0, a1, a2, a3, s0, s1, s2, s3);
                sum0 += s0; sum0 += s1; sum0 += s2; sum0 += s3;
            }
        }
#pragma unroll
        for (int p = 0; p < CQ; ++p) {
            if (4 * p < ncol1) {
                u64 q = colL1[p];
                const float* a0 = cmsS + (int)(q & 0xFFFFu) * 4 + b4;
                const float* a1 = cmsS + (int)((q >> 16) & 0xFFFFu) * 4 + b4;
                const float* a2 = cmsS + (int)((q >> 32) & 0xFFFFu) * 4 + b4;
                const float* a3 = cmsS + (int)(q >> 48) * 4 + b4;
                float s0, s1, s2, s3;
                ld4<LOCAL>(a0, a1, a2, a3, s0, s1, s2, s3);
                sum1 += s0; sum1 += s1; sum1 += s2; sum1 += s3;
            }
        }
        float nb0 = d * bel0 + (1.0f - d) * (llr0 + wcv * sum0);
        float nb1 = d * bel1 + (1.0f - d) * (llr1 + wcv * sum1);
        bel0 = nb0; bel1 = nb1;
        if (!last) {
            if (LOCAL) { *bel_own0 = nb0; *bel_own1 = nb1; }
            else { agent_stf(bel_own0, nb0); agent_stf(bel_own1, nb1); }
            grid_barrier(bars, barid++);
        } else {
            out[b * V_NUM + v0_my] = 1.0f / (1.0f + __expf(nb0));
            out[b * V_NUM + v1_my] = 1.0f / (1.0f + __expf(nb1));
        }
    }
}

__global__ __launch_bounds__(NTHR, 1)
void bp_fused(const float* __restrict__ H,      // (C, V)
              const float* __restrict__ synd,   // (B, C)
              const float* __restrict__ llr,    // (B, V)
              const float* __restrict__ w_vc_p,
              const float* __restrict__ w_cv_p,
              const float* __restrict__ damp_p,
              int* __restrict__ row_cnt, int* __restrict__ col_cnt,
              u16* __restrict__ row_idx, u16* __restrict__ col_idx,
              float* __restrict__ bel_x, float* __restrict__ cms_x,
              u32* __restrict__ bars, int* __restrict__ xcd_cnt,
              float* __restrict__ out) {        // (B, V)
    const int tid = blockIdx.x * NTHR + threadIdx.x;
    const int lane = threadIdx.x & 63;

    // ~116 KB static LDS: forces 1 block/CU -> 256 blocks land 1-per-CU
    // -> exactly 32 per XCD (checked at runtime anyway).
    __shared__ u32 lds_edges[(NTHR / 64) * WCAP + 1024];  // 20 KB (incl pad)
    __shared__ u64 ls_row[256 * RQ_S];                    // 26 KB
    __shared__ u64 ls_col[512 * CQ_S];                    // 36 KB
    __shared__ float4 ls_stage[(NTHR / 64) * 2 * 64];     // 32 KB: wave x slot x lane
    __shared__ int s_xcd, s_rank;
    u32* const wl = lds_edges + (threadIdx.x >> 6) * WCAP;

    // ---- XCD self-registration (counters host-zeroed) ----
    if (threadIdx.x == 0) {
        u32 x;
        asm volatile("s_getreg_b32 %0, hwreg(HW_REG_XCC_ID)" : "=s"(x));
        x &= 15;
        s_xcd = (int)x;
        s_rank = atomicAdd(&xcd_cnt[x], 1);   // device scope -> IF
    }

    // ---- P0: zero counters + zero dummy pads (agent -> IF) ----
    {
        u32* zp = (u32*)row_cnt;   // row_cnt..col_cnt contiguous, 96 KB
        for (int t = tid; t < ZERO_WORDS; t += NTH) agent_st32(&zp[t], 0u);
        if (tid < 32) {            // bel pads: slice g, dummy vi=16384
            int g = tid >> 2, j = tid & 3;
            agent_stf(&bel_x[(size_t)g * BEL_SL + V_NUM * 4 + j], 0.0f);
        } else if (tid < 64) {     // cms pads: slice g, dummy ci=8192
            int g = (tid - 32) >> 2, j = tid & 3;
            agent_stf(&cms_x[(size_t)g * CMS_SL + C_NUM * 4 + j], 0.0f);
        }
    }

    // ---- P1a: stream dense H through LDS (global_load_lds double-buffer),
    // compact nonzeros into per-wave LDS edge list. Counted vmcnt waits:
    // loop body has NO other vmem ops, and vmcnt(0) is drained beforehand.
    int wave_cnt;
    {
        const float4* Hv = (const float4*)H;
        const u64 ltmask = (1ull << lane) - 1ull;
        const int wid = threadIdx.x >> 6;
        const u32 gw = (u32)blockIdx.x * (NTHR / 64) + wid;   // 0..4095
        float4* const sl0 = &ls_stage[(wid * 2 + 0) * 64];
        float4* const sl1 = &ls_stage[(wid * 2 + 1) * 64];
        int wb = 0;

        asm volatile("s_waitcnt vmcnt(0)" ::: "memory");  // exact counting
        // prologue: chunk 0 -> slot 0 (1 KB per wave per instruction)
        __builtin_amdgcn_global_load_lds(
            (const u32*)(Hv + (((size_t)gw) << 6) + lane), (u32*)sl0, 16, 0, 0);

#pragma unroll 1
        for (int i = 0; i < SCAN_ITERS; ++i) {
            if (i + 1 < SCAN_ITERS) {
                const float4* gp = Hv + (((size_t)(gw + (u32)(i + 1) * NWAVE)) << 6) + lane;
                float4* lp = ((i + 1) & 1) ? sl1 : sl0;
                __builtin_amdgcn_global_load_lds((const u32*)gp, (u32*)lp, 16, 0, 0);
                asm volatile("s_waitcnt vmcnt(1)" ::: "memory");  // chunk i ready
            } else {
                asm volatile("s_waitcnt vmcnt(0)" ::: "memory");
            }
            __builtin_amdgcn_sched_barrier(0);
            const float4* sp = (i & 1) ? sl1 : sl0;
            float4 hv = sp[lane];
            int eb = (int)((gw + (u32)i * NWAVE) << 8);   // chunk elem base
            float vals[4] = {hv.x, hv.y, hv.z, hv.w};
#pragma unroll
            for (int k = 0; k < 4; ++k) {
                bool nz = vals[k] != 0.0f;
                u64 bb = __ballot(nz);
                if (bb) {
                    if (nz) {
                        int ee = eb + lane * 4 + k;
                        int off = wb + (int)__popcll(bb & ltmask);
                        if (off < WCAP) wl[off] = (u32)ee;
                    }
                    wb += (int)__popcll(bb);
                }
            }
        }
        wave_cnt = wb < WCAP ? wb : WCAP;
    }
    // Barrier: counters/pads zeroed everywhere; registrations complete.
    grid_barrier(bars, 0);

    // ---- P1b: CSR insertion from LDS edge lists (~33 edges/wave) ----
    {
        for (int e = lane; e < wave_cnt; e += 64) {
            u32 ee = wl[e];
            int c = (int)(ee >> 14);             // V = 2^14
            int v = (int)(ee & (V_NUM - 1));
            int rs = atomicAdd(&row_cnt[c], 1);  // device-scope -> IF
            if (rs < RW) agent_st16(&row_idx[(size_t)c * RW + rs], (u16)v);
            int cs = atomicAdd(&col_cnt[v], 1);
            if (cs < CW) agent_st16(&col_idx[(size_t)v * CW + cs], (u16)c);
        }
    }
    grid_barrier(bars, 1);

    // ---- group assignment: physical XCD if balanced, else virtual ----
    int my_xcd = s_xcd, my_rank = s_rank;   // visible post-barrier
    bool balanced = true;
#pragma unroll
    for (int g = 0; g < 8; ++g) balanced &= (agent_ldi(&xcd_cnt[g]) == 32);

    const float wvc = w_vc_p[0];
    const float wcv = w_cv_p[0];
    const float d   = damp_p[0];

    if (balanced) {
        decode_tail<true>(my_xcd, my_rank, synd, llr, row_cnt, col_cnt,
                          row_idx, col_idx, bel_x, cms_x, bars, out,
                          ls_row, ls_col, wvc, wcv, d);
    } else {
        decode_tail<false>((int)(blockIdx.x >> 5), (int)(blockIdx.x & 31),
                           synd, llr, row_cnt, col_cnt,
                           row_idx, col_idx, bel_x, cms_x, bars, out,
                           ls_row, ls_col, wvc, wcv, d);
    }
}

extern "C" void kernel_launch(void* const* d_in, const int* in_sizes, int n_in,
                              void* d_out, int out_size, void* d_ws, size_t ws_size,
                              hipStream_t stream) {
    const float* synd = (const float*)d_in[0];   // (B, C)
    const float* H    = (const float*)d_in[1];   // (C, V)
    const float* llr  = (const float*)d_in[2];   // (B, V)
    const float* w_vc = (const float*)d_in[3];
    const float* w_cv = (const float*)d_in[4];
    const float* damp = (const float*)d_in[5];
    float* out = (float*)d_out;

    char* ws = (char*)d_ws;
    size_t off = 0;
    int* row_cnt = (int*)(ws + off); off += (size_t)C_NUM * 4;        // 32 KB
    int* col_cnt = (int*)(ws + off); off += (size_t)V_NUM * 4;        // 64 KB
    u16* row_idx = (u16*)(ws + off); off += (size_t)C_NUM * RW * 2;   // 1 MB
    u16* col_idx = (u16*)(ws + off); off += (size_t)V_NUM * CW * 2;   // 1 MB
    float* bel_x = (float*)(ws + off); off += (size_t)8 * BEL_SL * 4; // 2.1 MB
    float* cms_x = (float*)(ws + off); off += (size_t)8 * CMS_SL * 4; // 1.05 MB
    u32* bars  = (u32*)(ws + off); off += (size_t)NBAR * 8 * BAR_STRIDE * 4; // 64 KB
    int* xcd_cnt = (int*)(ws + off); off += 64;                       // 16 ints

    // bars + xcd_cnt are contiguous: one memset covers both
    hipMemsetAsync(bars, 0, (size_t)NBAR * 8 * BAR_STRIDE * 4 + 64, stream);

    void* args[] = {
        (void*)&H, (void*)&synd, (void*)&llr,
        (void*)&w_vc, (void*)&w_cv, (void*)&damp,
        (void*)&row_cnt, (void*)&col_cnt, (void*)&row_idx, (void*)&col_idx,
        (void*)&bel_x, (void*)&cms_x, (void*)&bars, (void*)&xcd_cnt,
        (void*)&out
    };
    hipLaunchCooperativeKernel((const void*)bp_fused,
                               dim3(NBLK), dim3(NTHR), args, 0, stream);
}